// Round 12
// baseline (119.447 us; speedup 1.0000x reference)
//
#include <hip/hip_runtime.h>

#define N_PIX 4096
#define HW 64
#define NT 1024
#define NPK 2048          // peaks form an independent set => <= 2048
#define ALIVE_BIT (1ull << 63)
#define LEV44 0xFFFFFFFFFFFull
#define K2TAG 0x51170000u
#define POISON 0xAAAAAAAAu

__device__ __forceinline__ unsigned fmap_desc(float f) {
    unsigned u = __float_as_uint(f);
    unsigned m = u ^ (((unsigned)((int)u >> 31)) | 0x80000000u); // ascending map
    return ~m;                                                   // descending: smaller key = larger value
}
__device__ __forceinline__ float funmap_desc(unsigned k) {
    unsigned m = ~k;
    unsigned u = (m & 0x80000000u) ? (m ^ 0x80000000u) : ~m;
    return __uint_as_float(u);
}

// Lock-free triplet merge; node ids = collect order (arbitrary).
// T[x] alive : ALIVE_BIT | ownlev44   (lev = (KEY<<12)|pix, unique)
// T[x] dead  : (saddlelev44 << 12) | v  (component died, linked into v).
// Walk predicate (t>>12) > w stops at both {alive} and {dead at saddle > w}
// since ALIVE_BIT>>12 dwarfs any 44-bit lev. Elder = smaller lev; the walk's
// final read supplies the rep's state: alive => own lev inline, dead-later =>
// LEV[] read. CAS against that observed value (stale => CAS fails => retry).
// Links strictly lev-decreasing => acyclic; slot saddle only decreases.
__device__ void tm_merge(unsigned long long* T, const unsigned long long* LEV,
                         int a, int b, unsigned long long w) {
    for (int guard = 0; guard < (1 << 20); ++guard) {
        // interleaved dual walk: both dependent chains in flight at once
        int ra = a, rb = b;
        unsigned long long ta = *(volatile unsigned long long*)&T[ra];
        unsigned long long tb = *(volatile unsigned long long*)&T[rb];
        bool da = (ta >> 12) > w;
        bool db = (tb >> 12) > w;
        while (!(da && db)) {
            if (!da) { ra = (int)(ta & 0xFFFull); ta = *(volatile unsigned long long*)&T[ra]; da = (ta >> 12) > w; }
            if (!db) { rb = (int)(tb & 0xFFFull); tb = *(volatile unsigned long long*)&T[rb]; db = (tb >> 12) > w; }
        }
        if (ra == rb) return;
        unsigned long long la = (ta >> 63) ? (ta & LEV44) : LEV[ra];
        unsigned long long lb = (tb >> 63) ? (tb & LEV44) : LEV[rb];
        unsigned long long expect;
        if (la < lb) { int tt = ra; ra = rb; rb = tt; expect = tb; } // ra = younger
        else expect = ta;
        if (atomicCAS(&T[ra], expect, (w << 12) | (unsigned long long)rb) != expect)
            continue;                                   // raced/stale; re-walk
        if (expect >> 63) return;                       // was alive: done
        // displaced link re-hangs off rb's chain at its original saddle
        a = rb; b = (int)(expect & 0xFFFull); w = expect >> 12;
    }
}

extern "C" __global__ void __launch_bounds__(NT)
betti_fused_kernel(const float* __restrict__ logits,
                   const float* __restrict__ target,
                   float* __restrict__ out, unsigned* __restrict__ wsK) {
    __shared__ unsigned s_KEY[N_PIX];             // 16KB value keys
    __shared__ unsigned short s_LBL[N_PIX];       // 8KB  pixel -> basin peak pixel
    __shared__ unsigned short s_NIDX[N_PIX];      // 8KB  peak pixel -> node idx
    __shared__ unsigned long long s_LEV[NPK];     // 16KB node idx -> lev
    __shared__ unsigned long long s_TP[NPK];      // 16KB triplet slots
    __shared__ unsigned long long s_BK[NPK];      // 16KB bar selection keys
    __shared__ unsigned s_BAR[NPK];               // 8KB  (birthpix<<12)|deathpix
    __shared__ unsigned s_HIST[256];              // 1KB
    __shared__ unsigned long long s_l64[16];
    __shared__ float s_f32[16];
    __shared__ int s_anyf[20];
    __shared__ unsigned long long s_maxlev, s_pref, s_theta;
    __shared__ int s_np, s_cnt, s_done, s_rem, s_m, s_bin, s_bcnt, s_K2;

    const int d = blockIdx.x;        // 0..3 pred sample, 4..7 target sample
    const int smp = d & 3;
    const bool pred = d < 4;
    const int tid = threadIdx.x;
    const int lane = tid & 63, wid = tid >> 6;

    // ---- P0: value keys + fused max-lev reduction (essential death pixel) ----
    {
        unsigned long long ml = 0ull;
        if (pred) {
            for (int p = tid; p < N_PIX; p += NT) {
                float l0 = logits[smp * 2 * N_PIX + p];
                float l1 = logits[smp * 2 * N_PIX + N_PIX + p];
                float mx = fmaxf(l0, l1);
                float e0 = expf(l0 - mx), e1 = expf(l1 - mx);
                unsigned k = fmap_desc(e1 / (e0 + e1));
                s_KEY[p] = k;
                unsigned long long lv = ((unsigned long long)k << 12) | (unsigned)p;
                ml = (lv > ml) ? lv : ml;
            }
        } else {
            const float* tg = target + smp * N_PIX;
            const unsigned k1 = fmap_desc(1.0f), k0 = fmap_desc(0.0f);
            for (int p = tid; p < N_PIX; p += NT) {
                unsigned k = (tg[p] > 0.5f) ? k1 : k0;
                s_KEY[p] = k;
                unsigned long long lv = ((unsigned long long)k << 12) | (unsigned)p;
                ml = (lv > ml) ? lv : ml;
            }
        }
        #pragma unroll
        for (int off = 32; off > 0; off >>= 1) {
            unsigned long long o = __shfl_down(ml, off);
            ml = (o > ml) ? o : ml;
        }
        if (lane == 0) s_l64[wid] = ml;
        if (tid == 0) { s_np = 0; s_cnt = 0; }
        if (tid < 20) s_anyf[tid] = 0;
        __syncthreads();
        if (tid == 0) {
            unsigned long long mm = 0ull;
            for (int w = 0; w < 16; ++w) mm = (s_l64[w] > mm) ? s_l64[w] : mm;
            s_maxlev = mm;      // made visible to all by P2's next barrier
        }
    }

    // ---- P2: steepest-ascent basin pointers + 1-barrier/iter jumping ----
    for (int p = tid; p < N_PIX; p += NT) {
        int rr = p >> 6, cc = p & 63;
        unsigned long long best = ((unsigned long long)s_KEY[p] << 12) | (unsigned)p;
        int bj = p;
        if (rr > 0)  { int q = p - HW; unsigned long long l = ((unsigned long long)s_KEY[q] << 12) | (unsigned)q; if (l < best) { best = l; bj = q; } }
        if (rr < 63) { int q = p + HW; unsigned long long l = ((unsigned long long)s_KEY[q] << 12) | (unsigned)q; if (l < best) { best = l; bj = q; } }
        if (cc > 0)  { int q = p - 1;  unsigned long long l = ((unsigned long long)s_KEY[q] << 12) | (unsigned)q; if (l < best) { best = l; bj = q; } }
        if (cc < 63) { int q = p + 1;  unsigned long long l = ((unsigned long long)s_KEY[q] << 12) | (unsigned)q; if (l < best) { best = l; bj = q; } }
        s_LBL[p] = (unsigned short)bj;
    }
    __syncthreads();
    for (int it = 0; it < 14; ++it) {   // doubling; per-iter flag slot (no reset)
        bool ch = false;
        for (int p = tid; p < N_PIX; p += NT) {
            unsigned short a = s_LBL[p];
            unsigned short b = s_LBL[a];    // benign monotone race
            if (b != a) { s_LBL[p] = b; ch = true; }
        }
        if (ch) s_anyf[it] = 1;
        __syncthreads();
        if (!s_anyf[it]) break;             // uniform post-barrier read
    }

    // ---- P3: collect peaks (LBL[p]==p): node idx = collect order ----
    for (int p = tid; p < N_PIX; p += NT) {
        bool pk = ((int)s_LBL[p] == p);
        unsigned long long mk = __ballot(pk);
        int nb = __popcll(mk);
        int base = 0;
        if (lane == 0 && nb) base = atomicAdd(&s_np, nb);
        base = __shfl(base, 0);
        if (pk) {
            int pos = base + __popcll(mk & ((1ull << lane) - 1ull));
            unsigned long long lv = ((unsigned long long)s_KEY[p] << 12) | (unsigned)p;
            s_LEV[pos] = lv;
            s_TP[pos] = ALIVE_BIT | lv;
            s_NIDX[p] = (unsigned short)pos;
        }
    }
    __syncthreads();
    const int np = s_np;

    // ---- P5: cross-basin edges -> triplet merge (elder = smaller lev) ----
    for (int p = tid; p < N_PIX; p += NT) {
        int rr = p >> 6, cc = p & 63;
        int Lp = s_LBL[p];
        unsigned long long lp = ((unsigned long long)s_KEY[p] << 12) | (unsigned)p;
        if (cc < 63) {
            int q = p + 1; int Lq = s_LBL[q];
            if (Lq != Lp) {
                unsigned long long lq = ((unsigned long long)s_KEY[q] << 12) | (unsigned)q;
                tm_merge(s_TP, s_LEV, (int)s_NIDX[Lp], (int)s_NIDX[Lq], (lp > lq) ? lp : lq);
            }
        }
        if (rr < 63) {
            int q = p + HW; int Lq = s_LBL[q];
            if (Lq != Lp) {
                unsigned long long lq = ((unsigned long long)s_KEY[q] << 12) | (unsigned)q;
                tm_merge(s_TP, s_LEV, (int)s_NIDX[Lp], (int)s_NIDX[Lq], (lp > lq) ? lp : lq);
            }
        }
    }
    __syncthreads();

    const unsigned maxkey = (unsigned)(s_maxlev >> 12);
    const int maxpix = (int)(s_maxlev & 0xFFFull);

    if (!pred) {
        // ---- TARGET: K2 = #positive bars (alive node = essential), publish ----
        int cnt = 0;
        for (int x = tid; x < np; x += NT) {
            unsigned long long t = s_TP[x];
            unsigned dkey = (t >> 63) ? maxkey : (unsigned)(t >> 24);
            unsigned bkey = (unsigned)(s_LEV[x] >> 12);
            cnt += (bkey < dkey) ? 1 : 0;
        }
        for (int off = 32; off > 0; off >>= 1) cnt += __shfl_down(cnt, off);
        if (lane == 0) s_l64[wid] = (unsigned long long)cnt;
        __syncthreads();
        if (tid == 0) {
            int K2 = 0;
            for (int w = 0; w < 16; ++w) K2 += (int)s_l64[w];
            __threadfence();
            atomicExch(&wsK[smp], K2TAG | (unsigned)K2);
        }
        return;
    }

    // ---- PRED P6: collect positive bars + selection keys ----
    for (int x = tid; x < np; x += NT) {
        unsigned long long t = s_TP[x];
        unsigned long long lv = s_LEV[x];
        unsigned dkey; int dpix;
        if (t >> 63) { dkey = maxkey; dpix = maxpix; }
        else { dkey = (unsigned)(t >> 24); dpix = (int)((t >> 12) & 0xFFFull); }
        int bpix = (int)(lv & 0xFFFull);
        unsigned bkey = (unsigned)(lv >> 12);
        bool isb = bkey < dkey;          // strictly positive persistence
        unsigned rec = 0; unsigned long long bkv = 0;
        if (isb) {
            float pers = funmap_desc(bkey) - funmap_desc(dkey);
            rec = ((unsigned)bpix << 12) | (unsigned)dpix;
            bkv = ((unsigned long long)(~__float_as_uint(pers)) << 32) |
                  ((unsigned long long)x << 12) | (unsigned long long)dpix;
        }
        unsigned long long mk = __ballot(isb);
        int nb = __popcll(mk);
        int base = 0;
        if (lane == 0 && nb) base = atomicAdd(&s_cnt, nb);
        base = __shfl(base, 0);
        if (isb) {
            int pos = base + __popcll(mk & ((1ull << lane) - 1ull));
            s_BAR[pos] = rec; s_BK[pos] = bkv;
        }
    }
    __syncthreads();
    const int K1 = s_cnt;

    // ---- spin for target count (all 8 blocks co-resident on 256 CUs) ----
    if (tid == 0) {
        unsigned v;
        do { v = atomicAdd(&wsK[smp], 0u);
             __builtin_amdgcn_s_sleep(8);
        } while ((v >> 16) != (K2TAG >> 16));
        s_K2 = (int)(v & 0xFFFFu);
        s_m = min(K1, s_K2);
    }
    __syncthreads();
    const int m = s_m;

    // ---- P7: radix-select m-th smallest selection key -> theta ----
    unsigned long long theta = 0ull;
    if (m > 0) {
        if (tid == 0) { s_pref = 0ull; s_rem = m - 1; s_done = 0; }
        __syncthreads();
        for (int by = 7; by >= 0; --by) {
            if (s_done) break;                   // uniform post-barrier read
            if (tid < 256) s_HIST[tid] = 0;
            __syncthreads();
            unsigned long long pref = s_pref; int rem = s_rem;
            unsigned long long mhi = (by == 7) ? 0ull : (~0ull << ((by + 1) * 8));
            for (int e = tid; e < K1; e += NT) {
                unsigned long long k = s_BK[e];
                if ((k & mhi) == pref)
                    atomicAdd(&s_HIST[(unsigned)((k >> (by * 8)) & 255ull)], 1u);
            }
            __syncthreads();
            if (tid < 64) {
                unsigned h0 = s_HIST[4 * tid], h1 = s_HIST[4 * tid + 1];
                unsigned h2 = s_HIST[4 * tid + 2], h3 = s_HIST[4 * tid + 3];
                int lsx = (int)(h0 + h1 + h2 + h3);
                int xx = lsx;
                #pragma unroll
                for (int off = 1; off < 64; off <<= 1) { int t2 = __shfl_up(xx, off); if (tid >= off) xx += t2; }
                int excl = xx - lsx;
                if (rem >= excl && rem < excl + lsx) {
                    int rr = rem - excl; int b;
                    if (rr < (int)h0) b = 4 * tid;
                    else if (rr < (int)(h0 + h1)) { b = 4 * tid + 1; rr -= (int)h0; }
                    else if (rr < (int)(h0 + h1 + h2)) { b = 4 * tid + 2; rr -= (int)(h0 + h1); }
                    else { b = 4 * tid + 3; rr -= (int)(h0 + h1 + h2); }
                    s_bin = b; s_rem = rr; s_bcnt = (int)s_HIST[b];
                }
            }
            __syncthreads();
            unsigned long long npref = pref | ((unsigned long long)(unsigned)s_bin << (by * 8));
            if (tid == 0) s_pref = npref;
            if (s_bcnt == 1) {
                unsigned long long mcur = mhi | (0xFFull << (by * 8));
                for (int e = tid; e < K1; e += NT) {
                    unsigned long long k = s_BK[e];
                    if ((k & mcur) == npref) s_theta = k;   // unique writer
                }
                if (tid == 0) s_done = 1;
            }
            __syncthreads();
        }
        theta = s_theta;    // keys unique (node idx in low bits) => exit guaranteed
    }

    // ---- P8: loss + cross-block finisher (no separate memset kernel) ----
    float acc = 0.0f;
    for (int e = tid; e < K1; e += NT) {
        unsigned rec = s_BAR[e];
        float b = funmap_desc(s_KEY[rec >> 12]);
        float dd = funmap_desc(s_KEY[rec & 0xFFFu]);
        bool mt = (m > 0) && (s_BK[e] <= theta);
        float v1 = (b - 1.0f) * (b - 1.0f) + dd * dd;   // matched vs target (1,0)
        float v0 = 0.5f * (b - dd) * (b - dd);          // unmatched -> diagonal
        acc += mt ? v1 : v0;
    }
    if (tid == 0 && s_K2 > m) acc += 0.5f * (float)(s_K2 - m);  // unmatched (1,0)
    for (int off = 32; off > 0; off >>= 1) acc += __shfl_down(acc, off);
    if (lane == 0) s_f32[wid] = acc;
    __syncthreads();
    if (tid == 0) {
        float ls = 0.0f;
        for (int w = 0; w < 16; ++w) ls += s_f32[w];
        if (smp != 0) {
            // losses >= 0 => sign bit 0 => bits never equal POISON (sign bit 1)
            atomicExch(&wsK[4 + smp], __float_as_uint(ls));
        } else {
            float tot = ls;
            for (int j = 1; j < 4; ++j) {
                unsigned v;
                do { v = atomicAdd(&wsK[4 + j], 0u);
                     __builtin_amdgcn_s_sleep(8);
                } while (v == POISON);
                tot += __uint_as_float(v);
            }
            out[0] = 0.25f * tot;   // unconditional overwrite (out is poisoned)
        }
    }
}

extern "C" void kernel_launch(void* const* d_in, const int* in_sizes, int n_in,
                              void* d_out, int out_size, void* d_ws, size_t ws_size,
                              hipStream_t stream) {
    const float* logits = (const float*)d_in[0];   // (4,2,64,64) f32
    const float* target = (const float*)d_in[1];   // (4,64,64) f32
    unsigned* wsK = (unsigned*)d_ws;               // [0..3] K2 tags, [4..7] loss bits

    hipLaunchKernelGGL(betti_fused_kernel, dim3(8), dim3(NT), 0, stream,
                       logits, target, (float*)d_out, wsK);
}

// Round 13
// 102.330 us; speedup vs baseline: 1.1673x; 1.1673x over previous
//
#include <hip/hip_runtime.h>

#define N_PIX 4096
#define HW 64
#define NT 1024
#define NPK 2048          // peaks form an independent set => <= 2048
#define NEDG 8192         // cross-basin edges <= 8064
#define ALIVE_BIT (1ull << 63)
#define LEV44 0xFFFFFFFFFFFull
#define K2TAG 0x51170000u
#define POISON 0xAAAAAAAAu

__device__ __forceinline__ unsigned fmap_desc(float f) {
    unsigned u = __float_as_uint(f);
    unsigned m = u ^ (((unsigned)((int)u >> 31)) | 0x80000000u); // ascending map
    return ~m;                                                   // descending: smaller key = larger value
}
__device__ __forceinline__ float funmap_desc(unsigned k) {
    unsigned m = ~k;
    unsigned u = (m & 0x80000000u) ? (m ^ 0x80000000u) : ~m;
    return __uint_as_float(u);
}

// Lock-free triplet merge; node ids = collect order (arbitrary).
// T[x] alive : ALIVE_BIT | ownlev44   (lev = (KEY<<12)|pix, unique)
// T[x] dead  : (saddlelev44 << 12) | v  (component died, linked into v).
// Walk predicate (t>>12) > w stops at both {alive} and {dead at saddle > w}.
// Elder = smaller lev. r11's measured-best variant: sequential walks,
// re-read + staleness check before CAS (r12's dual-walk/CAS-observed was -6us).
__device__ void tm_merge(unsigned long long* T, const unsigned long long* LEV,
                         int a, int b, unsigned long long w) {
    for (int guard = 0; guard < (1 << 20); ++guard) {
        int ra = a; unsigned long long ta;
        while (true) {
            ta = *(volatile unsigned long long*)&T[ra];
            if ((ta >> 12) > w) break;
            ra = (int)(ta & 0xFFFull);
        }
        int rb = b; unsigned long long tb;
        while (true) {
            tb = *(volatile unsigned long long*)&T[rb];
            if ((tb >> 12) > w) break;
            rb = (int)(tb & 0xFFFull);
        }
        if (ra == rb) return;
        unsigned long long la = (ta >> 63) ? (ta & LEV44) : LEV[ra];
        unsigned long long lb = (tb >> 63) ? (tb & LEV44) : LEV[rb];
        if (la < lb) { int tt = ra; ra = rb; rb = tt; }   // ra = younger (bigger lev)
        unsigned long long old = *(volatile unsigned long long*)&T[ra];
        if ((old >> 12) <= w) continue;                   // stale rep; re-walk
        if (atomicCAS(&T[ra], old, (w << 12) | (unsigned long long)rb) != old)
            continue;                                     // lost race
        if (old >> 63) return;                            // was alive: done
        // displaced link re-hangs off rb's chain at its original saddle
        a = rb; b = (int)(old & 0xFFFull); w = old >> 12;
    }
}

extern "C" __global__ void __launch_bounds__(NT)
betti_fused_kernel(const float* __restrict__ logits,
                   const float* __restrict__ target,
                   float* __restrict__ out, unsigned* __restrict__ wsK) {
    __shared__ unsigned s_KEY[N_PIX];             // 16KB value keys
    __shared__ unsigned short s_LBL[N_PIX];       // 8KB  pixel -> basin peak pixel
    __shared__ unsigned short s_NIDX[N_PIX];      // 8KB  peak pixel -> node idx
    __shared__ unsigned long long s_LEV[NPK];     // 16KB node idx -> lev
    __shared__ unsigned long long s_TP[NPK];      // 16KB triplet slots
    __shared__ unsigned long long s_BK[NPK];      // 16KB bar selection keys
    __shared__ unsigned s_BAR[NPK];               // 8KB  (birthpix<<12)|deathpix
    __shared__ unsigned s_EDG[NEDG];              // 32KB (maxpix<<12)|other_nidx
    __shared__ unsigned s_HIST[256];              // 1KB
    __shared__ unsigned long long s_l64[16];
    __shared__ float s_f32[16];
    __shared__ int s_anyf[20];
    __shared__ unsigned long long s_maxlev, s_pref, s_theta;
    __shared__ int s_np, s_cnt, s_ne, s_done, s_rem, s_m, s_bin, s_bcnt, s_K2;

    const int d = blockIdx.x;        // 0..3 pred sample, 4..7 target sample
    const int smp = d & 3;
    const bool pred = d < 4;
    const int tid = threadIdx.x;
    const int lane = tid & 63, wid = tid >> 6;

    // ---- P0: value keys + fused max-lev reduction (essential death pixel) ----
    {
        unsigned long long ml = 0ull;
        if (pred) {
            for (int p = tid; p < N_PIX; p += NT) {
                float l0 = logits[smp * 2 * N_PIX + p];
                float l1 = logits[smp * 2 * N_PIX + N_PIX + p];
                float mx = fmaxf(l0, l1);
                float e0 = expf(l0 - mx), e1 = expf(l1 - mx);
                unsigned k = fmap_desc(e1 / (e0 + e1));
                s_KEY[p] = k;
                unsigned long long lv = ((unsigned long long)k << 12) | (unsigned)p;
                ml = (lv > ml) ? lv : ml;
            }
        } else {
            const float* tg = target + smp * N_PIX;
            const unsigned k1 = fmap_desc(1.0f), k0 = fmap_desc(0.0f);
            for (int p = tid; p < N_PIX; p += NT) {
                unsigned k = (tg[p] > 0.5f) ? k1 : k0;
                s_KEY[p] = k;
                unsigned long long lv = ((unsigned long long)k << 12) | (unsigned)p;
                ml = (lv > ml) ? lv : ml;
            }
        }
        #pragma unroll
        for (int off = 32; off > 0; off >>= 1) {
            unsigned long long o = __shfl_down(ml, off);
            ml = (o > ml) ? o : ml;
        }
        if (lane == 0) s_l64[wid] = ml;
        if (tid == 0) { s_np = 0; s_cnt = 0; s_ne = 0; }
        if (tid < 20) s_anyf[tid] = 0;
        __syncthreads();
        if (tid == 0) {
            unsigned long long mm = 0ull;
            for (int w = 0; w < 16; ++w) mm = (s_l64[w] > mm) ? s_l64[w] : mm;
            s_maxlev = mm;      // made visible to all by P2's next barrier
        }
    }

    // ---- P2: steepest-ascent basin pointers + 1-barrier/iter jumping ----
    for (int p = tid; p < N_PIX; p += NT) {
        int rr = p >> 6, cc = p & 63;
        unsigned long long best = ((unsigned long long)s_KEY[p] << 12) | (unsigned)p;
        int bj = p;
        if (rr > 0)  { int q = p - HW; unsigned long long l = ((unsigned long long)s_KEY[q] << 12) | (unsigned)q; if (l < best) { best = l; bj = q; } }
        if (rr < 63) { int q = p + HW; unsigned long long l = ((unsigned long long)s_KEY[q] << 12) | (unsigned)q; if (l < best) { best = l; bj = q; } }
        if (cc > 0)  { int q = p - 1;  unsigned long long l = ((unsigned long long)s_KEY[q] << 12) | (unsigned)q; if (l < best) { best = l; bj = q; } }
        if (cc < 63) { int q = p + 1;  unsigned long long l = ((unsigned long long)s_KEY[q] << 12) | (unsigned)q; if (l < best) { best = l; bj = q; } }
        s_LBL[p] = (unsigned short)bj;
    }
    __syncthreads();
    for (int it = 0; it < 14; ++it) {   // doubling; per-iter flag slot (no reset)
        bool ch = false;
        for (int p = tid; p < N_PIX; p += NT) {
            unsigned short a = s_LBL[p];
            unsigned short b = s_LBL[a];    // benign monotone race
            if (b != a) { s_LBL[p] = b; ch = true; }
        }
        if (ch) s_anyf[it] = 1;
        __syncthreads();
        if (!s_anyf[it]) break;             // uniform post-barrier read
    }

    // ---- P3: collect peaks (LBL[p]==p): node idx = collect order ----
    for (int p = tid; p < N_PIX; p += NT) {
        bool pk = ((int)s_LBL[p] == p);
        unsigned long long mk = __ballot(pk);
        int nb = __popcll(mk);
        int base = 0;
        if (lane == 0 && nb) base = atomicAdd(&s_np, nb);
        base = __shfl(base, 0);
        if (pk) {
            int pos = base + __popcll(mk & ((1ull << lane) - 1ull));
            unsigned long long lv = ((unsigned long long)s_KEY[p] << 12) | (unsigned)p;
            s_LEV[pos] = lv;
            s_TP[pos] = ALIVE_BIT | lv;
            s_NIDX[p] = (unsigned short)pos;
        }
    }
    __syncthreads();
    const int np = s_np;

    // ---- P4: build cross-basin edge worklist (wave-aggregated push) ----
    // record = (max_endpoint_pixel << 12) | other_side_node_idx; w and own
    // node idx re-derived at merge time (keeps record in 24 bits / u32).
    for (int p = tid; p < N_PIX; p += NT) {
        int rr = p >> 6, cc = p & 63;
        int Lp = s_LBL[p];
        unsigned long long lp = ((unsigned long long)s_KEY[p] << 12) | (unsigned)p;
        unsigned e0 = 0, e1 = 0;
        bool v0 = false, v1 = false;
        if (cc < 63) {
            int q = p + 1; int Lq = s_LBL[q];
            if (Lq != Lp) {
                unsigned long long lq = ((unsigned long long)s_KEY[q] << 12) | (unsigned)q;
                int mx = (lp > lq) ? p : q;
                int ob = (lp > lq) ? Lq : Lp;
                e0 = ((unsigned)mx << 12) | (unsigned)s_NIDX[ob];
                v0 = true;
            }
        }
        if (rr < 63) {
            int q = p + HW; int Lq = s_LBL[q];
            if (Lq != Lp) {
                unsigned long long lq = ((unsigned long long)s_KEY[q] << 12) | (unsigned)q;
                int mx = (lp > lq) ? p : q;
                int ob = (lp > lq) ? Lq : Lp;
                e1 = ((unsigned)mx << 12) | (unsigned)s_NIDX[ob];
                v1 = true;
            }
        }
        unsigned long long m0 = __ballot(v0);
        unsigned long long m1 = __ballot(v1);
        int nb = __popcll(m0) + __popcll(m1);
        int base = 0;
        if (lane == 0 && nb) base = atomicAdd(&s_ne, nb);
        base = __shfl(base, 0);
        unsigned long long ltm = (1ull << lane) - 1ull;
        if (v0) s_EDG[base + __popcll(m0 & ltm)] = e0;
        if (v1) s_EDG[base + __popcll(m0) + __popcll(m1 & ltm)] = e1;
    }
    __syncthreads();
    const int nE = s_ne;

    // ---- P5: balanced triplet merge over the worklist ----
    for (int e = tid; e < nE; e += NT) {
        unsigned rec = s_EDG[e];
        int mx = (int)(rec >> 12);
        int bidx = (int)(rec & 0xFFFu);
        int aidx = (int)s_NIDX[s_LBL[mx]];
        unsigned long long w = ((unsigned long long)s_KEY[mx] << 12) | (unsigned)mx;
        tm_merge(s_TP, s_LEV, aidx, bidx, w);
    }
    __syncthreads();

    const unsigned maxkey = (unsigned)(s_maxlev >> 12);
    const int maxpix = (int)(s_maxlev & 0xFFFull);

    if (!pred) {
        // ---- TARGET: K2 = #positive bars (alive node = essential), publish ----
        int cnt = 0;
        for (int x = tid; x < np; x += NT) {
            unsigned long long t = s_TP[x];
            unsigned dkey = (t >> 63) ? maxkey : (unsigned)(t >> 24);
            unsigned bkey = (unsigned)(s_LEV[x] >> 12);
            cnt += (bkey < dkey) ? 1 : 0;
        }
        for (int off = 32; off > 0; off >>= 1) cnt += __shfl_down(cnt, off);
        if (lane == 0) s_l64[wid] = (unsigned long long)cnt;
        __syncthreads();
        if (tid == 0) {
            int K2 = 0;
            for (int w = 0; w < 16; ++w) K2 += (int)s_l64[w];
            __threadfence();
            atomicExch(&wsK[smp], K2TAG | (unsigned)K2);
        }
        return;
    }

    // ---- PRED P6: collect positive bars + selection keys ----
    for (int x = tid; x < np; x += NT) {
        unsigned long long t = s_TP[x];
        unsigned long long lv = s_LEV[x];
        unsigned dkey; int dpix;
        if (t >> 63) { dkey = maxkey; dpix = maxpix; }
        else { dkey = (unsigned)(t >> 24); dpix = (int)((t >> 12) & 0xFFFull); }
        int bpix = (int)(lv & 0xFFFull);
        unsigned bkey = (unsigned)(lv >> 12);
        bool isb = bkey < dkey;          // strictly positive persistence
        unsigned rec = 0; unsigned long long bkv = 0;
        if (isb) {
            float pers = funmap_desc(bkey) - funmap_desc(dkey);
            rec = ((unsigned)bpix << 12) | (unsigned)dpix;
            bkv = ((unsigned long long)(~__float_as_uint(pers)) << 32) |
                  ((unsigned long long)x << 12) | (unsigned long long)dpix;
        }
        unsigned long long mk = __ballot(isb);
        int nb = __popcll(mk);
        int base = 0;
        if (lane == 0 && nb) base = atomicAdd(&s_cnt, nb);
        base = __shfl(base, 0);
        if (isb) {
            int pos = base + __popcll(mk & ((1ull << lane) - 1ull));
            s_BAR[pos] = rec; s_BK[pos] = bkv;
        }
    }
    __syncthreads();
    const int K1 = s_cnt;

    // ---- spin for target count (all 8 blocks co-resident on 256 CUs) ----
    if (tid == 0) {
        unsigned v;
        do { v = atomicAdd(&wsK[smp], 0u);
             __builtin_amdgcn_s_sleep(8);
        } while ((v >> 16) != (K2TAG >> 16));
        s_K2 = (int)(v & 0xFFFFu);
        s_m = min(K1, s_K2);
    }
    __syncthreads();
    const int m = s_m;

    // ---- P7: radix-select m-th smallest selection key -> theta ----
    unsigned long long theta = 0ull;
    if (m > 0) {
        if (tid == 0) { s_pref = 0ull; s_rem = m - 1; s_done = 0; }
        __syncthreads();
        for (int by = 7; by >= 0; --by) {
            if (s_done) break;                   // uniform post-barrier read
            if (tid < 256) s_HIST[tid] = 0;
            __syncthreads();
            unsigned long long pref = s_pref; int rem = s_rem;
            unsigned long long mhi = (by == 7) ? 0ull : (~0ull << ((by + 1) * 8));
            for (int e = tid; e < K1; e += NT) {
                unsigned long long k = s_BK[e];
                if ((k & mhi) == pref)
                    atomicAdd(&s_HIST[(unsigned)((k >> (by * 8)) & 255ull)], 1u);
            }
            __syncthreads();
            if (tid < 64) {
                unsigned h0 = s_HIST[4 * tid], h1 = s_HIST[4 * tid + 1];
                unsigned h2 = s_HIST[4 * tid + 2], h3 = s_HIST[4 * tid + 3];
                int lsx = (int)(h0 + h1 + h2 + h3);
                int xx = lsx;
                #pragma unroll
                for (int off = 1; off < 64; off <<= 1) { int t2 = __shfl_up(xx, off); if (tid >= off) xx += t2; }
                int excl = xx - lsx;
                if (rem >= excl && rem < excl + lsx) {
                    int rr = rem - excl; int b;
                    if (rr < (int)h0) b = 4 * tid;
                    else if (rr < (int)(h0 + h1)) { b = 4 * tid + 1; rr -= (int)h0; }
                    else if (rr < (int)(h0 + h1 + h2)) { b = 4 * tid + 2; rr -= (int)(h0 + h1); }
                    else { b = 4 * tid + 3; rr -= (int)(h0 + h1 + h2); }
                    s_bin = b; s_rem = rr; s_bcnt = (int)s_HIST[b];
                }
            }
            __syncthreads();
            unsigned long long npref = pref | ((unsigned long long)(unsigned)s_bin << (by * 8));
            if (tid == 0) s_pref = npref;
            if (s_bcnt == 1) {
                unsigned long long mcur = mhi | (0xFFull << (by * 8));
                for (int e = tid; e < K1; e += NT) {
                    unsigned long long k = s_BK[e];
                    if ((k & mcur) == npref) s_theta = k;   // unique writer
                }
                if (tid == 0) s_done = 1;
            }
            __syncthreads();
        }
        theta = s_theta;    // keys unique (node idx in low bits) => exit guaranteed
    }

    // ---- P8: loss + cross-block finisher (no separate memset kernel) ----
    float acc = 0.0f;
    for (int e = tid; e < K1; e += NT) {
        unsigned rec = s_BAR[e];
        float b = funmap_desc(s_KEY[rec >> 12]);
        float dd = funmap_desc(s_KEY[rec & 0xFFFu]);
        bool mt = (m > 0) && (s_BK[e] <= theta);
        float v1 = (b - 1.0f) * (b - 1.0f) + dd * dd;   // matched vs target (1,0)
        float v0 = 0.5f * (b - dd) * (b - dd);          // unmatched -> diagonal
        acc += mt ? v1 : v0;
    }
    if (tid == 0 && s_K2 > m) acc += 0.5f * (float)(s_K2 - m);  // unmatched (1,0)
    for (int off = 32; off > 0; off >>= 1) acc += __shfl_down(acc, off);
    if (lane == 0) s_f32[wid] = acc;
    __syncthreads();
    if (tid == 0) {
        float ls = 0.0f;
        for (int w = 0; w < 16; ++w) ls += s_f32[w];
        if (smp != 0) {
            // losses >= 0 => sign bit 0 => bits never equal POISON (sign bit 1)
            atomicExch(&wsK[4 + smp], __float_as_uint(ls));
        } else {
            float tot = ls;
            for (int j = 1; j < 4; ++j) {
                unsigned v;
                do { v = atomicAdd(&wsK[4 + j], 0u);
                     __builtin_amdgcn_s_sleep(8);
                } while (v == POISON);
                tot += __uint_as_float(v);
            }
            out[0] = 0.25f * tot;   // unconditional overwrite (out is poisoned)
        }
    }
}

extern "C" void kernel_launch(void* const* d_in, const int* in_sizes, int n_in,
                              void* d_out, int out_size, void* d_ws, size_t ws_size,
                              hipStream_t stream) {
    const float* logits = (const float*)d_in[0];   // (4,2,64,64) f32
    const float* target = (const float*)d_in[1];   // (4,64,64) f32
    unsigned* wsK = (unsigned*)d_ws;               // [0..3] K2 tags, [4..7] loss bits

    hipLaunchKernelGGL(betti_fused_kernel, dim3(8), dim3(NT), 0, stream,
                       logits, target, (float*)d_out, wsK);
}

// Round 14
// 102.126 us; speedup vs baseline: 1.1696x; 1.0020x over previous
//
#include <hip/hip_runtime.h>

#define N_PIX 4096
#define HW 64
#define NT 1024
#define NPK 2048          // peaks form an independent set => <= 2048
#define NEDG 8192         // cross-basin edges <= 8064
#define ALIVE_BIT (1ull << 63)
#define LEV44 0xFFFFFFFFFFFull
#define K2TAG 0x51170000u
#define POISON 0xAAAAAAAAu

__device__ __forceinline__ unsigned fmap_desc(float f) {
    unsigned u = __float_as_uint(f);
    unsigned m = u ^ (((unsigned)((int)u >> 31)) | 0x80000000u); // ascending map
    return ~m;                                                   // descending: smaller key = larger value
}
__device__ __forceinline__ float funmap_desc(unsigned k) {
    unsigned m = ~k;
    unsigned u = (m & 0x80000000u) ? (m ^ 0x80000000u) : ~m;
    return __uint_as_float(u);
}

// Lock-free triplet merge; node ids = collect order (arbitrary).
// T[x] alive : ALIVE_BIT | ownlev44   (lev = (KEY<<12)|pix, unique)
// T[x] dead  : (saddlelev44 << 12) | v  (component died, linked into v).
// Walk predicate (t>>12) > w stops at both {alive} and {dead at saddle > w}.
// Elder = smaller lev. r11's measured-best variant: sequential walks,
// re-read + staleness check before CAS (r12's dual-walk/CAS-observed was -6us).
__device__ void tm_merge(unsigned long long* T, const unsigned long long* LEV,
                         int a, int b, unsigned long long w) {
    for (int guard = 0; guard < (1 << 20); ++guard) {
        int ra = a; unsigned long long ta;
        while (true) {
            ta = *(volatile unsigned long long*)&T[ra];
            if ((ta >> 12) > w) break;
            ra = (int)(ta & 0xFFFull);
        }
        int rb = b; unsigned long long tb;
        while (true) {
            tb = *(volatile unsigned long long*)&T[rb];
            if ((tb >> 12) > w) break;
            rb = (int)(tb & 0xFFFull);
        }
        if (ra == rb) return;
        unsigned long long la = (ta >> 63) ? (ta & LEV44) : LEV[ra];
        unsigned long long lb = (tb >> 63) ? (tb & LEV44) : LEV[rb];
        if (la < lb) { int tt = ra; ra = rb; rb = tt; }   // ra = younger (bigger lev)
        unsigned long long old = *(volatile unsigned long long*)&T[ra];
        if ((old >> 12) <= w) continue;                   // stale rep; re-walk
        if (atomicCAS(&T[ra], old, (w << 12) | (unsigned long long)rb) != old)
            continue;                                     // lost race
        if (old >> 63) return;                            // was alive: done
        // displaced link re-hangs off rb's chain at its original saddle
        a = rb; b = (int)(old & 0xFFFull); w = old >> 12;
    }
}

extern "C" __global__ void __launch_bounds__(NT)
betti_fused_kernel(const float* __restrict__ logits,
                   const float* __restrict__ target,
                   float* __restrict__ out, unsigned* __restrict__ wsK) {
    __shared__ unsigned s_KEY[N_PIX];             // 16KB value keys
    __shared__ unsigned short s_LBL[N_PIX];       // 8KB  pixel -> basin peak pixel
    __shared__ unsigned short s_NIDX[N_PIX];      // 8KB  peak pixel -> node idx
    __shared__ unsigned long long s_LEV[NPK];     // 16KB node idx -> lev
    __shared__ unsigned long long s_TP[NPK];      // 16KB triplet slots
    __shared__ unsigned long long s_BK[NPK];      // 16KB bar selection keys
    __shared__ unsigned s_BAR[NPK];               // 8KB  (birthpix<<12)|deathpix
    __shared__ unsigned s_EDG[NEDG];              // 32KB (maxpix<<12)|other_nidx
    __shared__ unsigned s_HISTb[2][256];          // 2KB  double-buffered histograms
    __shared__ unsigned long long s_l64[16];
    __shared__ float s_f32[16];
    __shared__ int s_anyf[20];
    __shared__ unsigned long long s_maxlev, s_pref, s_theta;
    __shared__ int s_np, s_cnt, s_ne, s_done, s_rem, s_m, s_bin, s_bcnt, s_K2;

    const int d = blockIdx.x;        // 0..3 pred sample, 4..7 target sample
    const int smp = d & 3;
    const bool pred = d < 4;
    const int tid = threadIdx.x;
    const int lane = tid & 63, wid = tid >> 6;

    // ---- P0: value keys (float4 loads, 4 px/thread) + fused max-lev ----
    {
        unsigned long long ml = 0ull;
        const int p4 = tid * 4;               // 4096 = 4 * 1024 exactly
        if (pred) {
            const float4 L0 = *(const float4*)(logits + smp * 2 * N_PIX + p4);
            const float4 L1 = *(const float4*)(logits + smp * 2 * N_PIX + N_PIX + p4);
            const float l0a[4] = { L0.x, L0.y, L0.z, L0.w };
            const float l1a[4] = { L1.x, L1.y, L1.z, L1.w };
            #pragma unroll
            for (int j = 0; j < 4; ++j) {
                float mx = fmaxf(l0a[j], l1a[j]);
                float e0 = expf(l0a[j] - mx), e1 = expf(l1a[j] - mx);
                unsigned k = fmap_desc(e1 / (e0 + e1));
                s_KEY[p4 + j] = k;
                unsigned long long lv = ((unsigned long long)k << 12) | (unsigned)(p4 + j);
                ml = (lv > ml) ? lv : ml;
            }
        } else {
            const float4 Tg = *(const float4*)(target + smp * N_PIX + p4);
            const float ta[4] = { Tg.x, Tg.y, Tg.z, Tg.w };
            const unsigned k1 = fmap_desc(1.0f), k0 = fmap_desc(0.0f);
            #pragma unroll
            for (int j = 0; j < 4; ++j) {
                unsigned k = (ta[j] > 0.5f) ? k1 : k0;
                s_KEY[p4 + j] = k;
                unsigned long long lv = ((unsigned long long)k << 12) | (unsigned)(p4 + j);
                ml = (lv > ml) ? lv : ml;
            }
        }
        #pragma unroll
        for (int off = 32; off > 0; off >>= 1) {
            unsigned long long o = __shfl_down(ml, off);
            ml = (o > ml) ? o : ml;
        }
        if (lane == 0) s_l64[wid] = ml;
        if (tid == 0) { s_np = 0; s_cnt = 0; s_ne = 0; }
        if (tid < 20) s_anyf[tid] = 0;
        __syncthreads();
        if (tid == 0) {
            unsigned long long mm = 0ull;
            for (int w = 0; w < 16; ++w) mm = (s_l64[w] > mm) ? s_l64[w] : mm;
            s_maxlev = mm;      // made visible to all by P2's next barrier
        }
    }

    // ---- P2: steepest-ascent basin pointers + 1-barrier/iter jumping ----
    for (int p = tid; p < N_PIX; p += NT) {
        int rr = p >> 6, cc = p & 63;
        unsigned long long best = ((unsigned long long)s_KEY[p] << 12) | (unsigned)p;
        int bj = p;
        if (rr > 0)  { int q = p - HW; unsigned long long l = ((unsigned long long)s_KEY[q] << 12) | (unsigned)q; if (l < best) { best = l; bj = q; } }
        if (rr < 63) { int q = p + HW; unsigned long long l = ((unsigned long long)s_KEY[q] << 12) | (unsigned)q; if (l < best) { best = l; bj = q; } }
        if (cc > 0)  { int q = p - 1;  unsigned long long l = ((unsigned long long)s_KEY[q] << 12) | (unsigned)q; if (l < best) { best = l; bj = q; } }
        if (cc < 63) { int q = p + 1;  unsigned long long l = ((unsigned long long)s_KEY[q] << 12) | (unsigned)q; if (l < best) { best = l; bj = q; } }
        s_LBL[p] = (unsigned short)bj;
    }
    __syncthreads();
    for (int it = 0; it < 14; ++it) {   // doubling; per-iter flag slot (no reset)
        bool ch = false;
        for (int p = tid; p < N_PIX; p += NT) {
            unsigned short a = s_LBL[p];
            unsigned short b = s_LBL[a];    // benign monotone race
            if (b != a) { s_LBL[p] = b; ch = true; }
        }
        if (ch) s_anyf[it] = 1;
        __syncthreads();
        if (!s_anyf[it]) break;             // uniform post-barrier read
    }

    // ---- P3: collect peaks (LBL[p]==p): node idx = collect order ----
    for (int p = tid; p < N_PIX; p += NT) {
        bool pk = ((int)s_LBL[p] == p);
        unsigned long long mk = __ballot(pk);
        int nb = __popcll(mk);
        int base = 0;
        if (lane == 0 && nb) base = atomicAdd(&s_np, nb);
        base = __shfl(base, 0);
        if (pk) {
            int pos = base + __popcll(mk & ((1ull << lane) - 1ull));
            unsigned long long lv = ((unsigned long long)s_KEY[p] << 12) | (unsigned)p;
            s_LEV[pos] = lv;
            s_TP[pos] = ALIVE_BIT | lv;
            s_NIDX[p] = (unsigned short)pos;
        }
    }
    __syncthreads();
    const int np = s_np;

    // ---- P4: build cross-basin edge worklist (wave-aggregated push) ----
    // record = (max_endpoint_pixel << 12) | other_side_node_idx; w and own
    // node idx re-derived at merge time (keeps record in 24 bits / u32).
    for (int p = tid; p < N_PIX; p += NT) {
        int rr = p >> 6, cc = p & 63;
        int Lp = s_LBL[p];
        unsigned long long lp = ((unsigned long long)s_KEY[p] << 12) | (unsigned)p;
        unsigned e0 = 0, e1 = 0;
        bool v0 = false, v1 = false;
        if (cc < 63) {
            int q = p + 1; int Lq = s_LBL[q];
            if (Lq != Lp) {
                unsigned long long lq = ((unsigned long long)s_KEY[q] << 12) | (unsigned)q;
                int mx = (lp > lq) ? p : q;
                int ob = (lp > lq) ? Lq : Lp;
                e0 = ((unsigned)mx << 12) | (unsigned)s_NIDX[ob];
                v0 = true;
            }
        }
        if (rr < 63) {
            int q = p + HW; int Lq = s_LBL[q];
            if (Lq != Lp) {
                unsigned long long lq = ((unsigned long long)s_KEY[q] << 12) | (unsigned)q;
                int mx = (lp > lq) ? p : q;
                int ob = (lp > lq) ? Lq : Lp;
                e1 = ((unsigned)mx << 12) | (unsigned)s_NIDX[ob];
                v1 = true;
            }
        }
        unsigned long long m0 = __ballot(v0);
        unsigned long long m1 = __ballot(v1);
        int nb = __popcll(m0) + __popcll(m1);
        int base = 0;
        if (lane == 0 && nb) base = atomicAdd(&s_ne, nb);
        base = __shfl(base, 0);
        unsigned long long ltm = (1ull << lane) - 1ull;
        if (v0) s_EDG[base + __popcll(m0 & ltm)] = e0;
        if (v1) s_EDG[base + __popcll(m0) + __popcll(m1 & ltm)] = e1;
    }
    __syncthreads();
    const int nE = s_ne;

    // ---- P5: balanced triplet merge over the worklist ----
    for (int e = tid; e < nE; e += NT) {
        unsigned rec = s_EDG[e];
        int mx = (int)(rec >> 12);
        int bidx = (int)(rec & 0xFFFu);
        int aidx = (int)s_NIDX[s_LBL[mx]];
        unsigned long long w = ((unsigned long long)s_KEY[mx] << 12) | (unsigned)mx;
        tm_merge(s_TP, s_LEV, aidx, bidx, w);
    }
    __syncthreads();

    const unsigned maxkey = (unsigned)(s_maxlev >> 12);
    const int maxpix = (int)(s_maxlev & 0xFFFull);

    if (!pred) {
        // ---- TARGET: K2 = #positive bars (alive node = essential), publish ----
        int cnt = 0;
        for (int x = tid; x < np; x += NT) {
            unsigned long long t = s_TP[x];
            unsigned dkey = (t >> 63) ? maxkey : (unsigned)(t >> 24);
            unsigned bkey = (unsigned)(s_LEV[x] >> 12);
            cnt += (bkey < dkey) ? 1 : 0;
        }
        for (int off = 32; off > 0; off >>= 1) cnt += __shfl_down(cnt, off);
        if (lane == 0) s_l64[wid] = (unsigned long long)cnt;
        __syncthreads();
        if (tid == 0) {
            int K2 = 0;
            for (int w = 0; w < 16; ++w) K2 += (int)s_l64[w];
            __threadfence();
            atomicExch(&wsK[smp], K2TAG | (unsigned)K2);
        }
        return;
    }

    // ---- PRED P6: collect positive bars + selection keys ----
    for (int x = tid; x < np; x += NT) {
        unsigned long long t = s_TP[x];
        unsigned long long lv = s_LEV[x];
        unsigned dkey; int dpix;
        if (t >> 63) { dkey = maxkey; dpix = maxpix; }
        else { dkey = (unsigned)(t >> 24); dpix = (int)((t >> 12) & 0xFFFull); }
        int bpix = (int)(lv & 0xFFFull);
        unsigned bkey = (unsigned)(lv >> 12);
        bool isb = bkey < dkey;          // strictly positive persistence
        unsigned rec = 0; unsigned long long bkv = 0;
        if (isb) {
            float pers = funmap_desc(bkey) - funmap_desc(dkey);
            rec = ((unsigned)bpix << 12) | (unsigned)dpix;
            bkv = ((unsigned long long)(~__float_as_uint(pers)) << 32) |
                  ((unsigned long long)x << 12) | (unsigned long long)dpix;
        }
        unsigned long long mk = __ballot(isb);
        int nb = __popcll(mk);
        int base = 0;
        if (lane == 0 && nb) base = atomicAdd(&s_cnt, nb);
        base = __shfl(base, 0);
        if (isb) {
            int pos = base + __popcll(mk & ((1ull << lane) - 1ull));
            s_BAR[pos] = rec; s_BK[pos] = bkv;
        }
    }
    __syncthreads();
    const int K1 = s_cnt;

    // ---- spin for target count; fused P7 init (idle threads zero hists) ----
    if (tid >= 512) {            // zero both select histograms behind this barrier
        s_HISTb[0][tid & 255] = 0;
        s_HISTb[1][tid & 255] = 0;
    }
    if (tid == 0) {
        unsigned v;
        do { v = atomicAdd(&wsK[smp], 0u);
             __builtin_amdgcn_s_sleep(8);
        } while ((v >> 16) != (K2TAG >> 16));
        s_K2 = (int)(v & 0xFFFFu);
        int mloc = min(K1, s_K2);
        s_m = mloc;
        s_pref = 0ull; s_rem = mloc - 1; s_done = 0;
    }
    __syncthreads();
    const int m = s_m;

    // ---- P7: radix-select m-th smallest key (3 barriers/round, dbuf hist) ----
    unsigned long long theta = 0ull;
    if (m > 0) {
        int rb = 0;
        for (int by = 7; by >= 0; --by, rb ^= 1) {
            if (s_done) break;                   // uniform post-barrier read
            unsigned* H = s_HISTb[rb];
            unsigned long long pref = s_pref; int rem = s_rem;
            unsigned long long mhi = (by == 7) ? 0ull : (~0ull << ((by + 1) * 8));
            for (int e = tid; e < K1; e += NT) {
                unsigned long long k = s_BK[e];
                if ((k & mhi) == pref)
                    atomicAdd(&H[(unsigned)((k >> (by * 8)) & 255ull)], 1u);
            }
            __syncthreads();
            // pick phase: tid<64 scans; tid>=512 zeroes the other buffer
            if (tid >= 512 && tid < 768) s_HISTb[rb ^ 1][tid - 512] = 0;
            if (tid < 64) {
                unsigned h0 = H[4 * tid], h1 = H[4 * tid + 1];
                unsigned h2 = H[4 * tid + 2], h3 = H[4 * tid + 3];
                int lsx = (int)(h0 + h1 + h2 + h3);
                int xx = lsx;
                #pragma unroll
                for (int off = 1; off < 64; off <<= 1) { int t2 = __shfl_up(xx, off); if (tid >= off) xx += t2; }
                int excl = xx - lsx;
                if (rem >= excl && rem < excl + lsx) {
                    int rr = rem - excl; int b;
                    if (rr < (int)h0) b = 4 * tid;
                    else if (rr < (int)(h0 + h1)) { b = 4 * tid + 1; rr -= (int)h0; }
                    else if (rr < (int)(h0 + h1 + h2)) { b = 4 * tid + 2; rr -= (int)(h0 + h1); }
                    else { b = 4 * tid + 3; rr -= (int)(h0 + h1 + h2); }
                    s_bin = b; s_rem = rr; s_bcnt = (int)H[b];
                }
            }
            __syncthreads();
            unsigned long long npref = pref | ((unsigned long long)(unsigned)s_bin << (by * 8));
            if (tid == 0) s_pref = npref;
            if (s_bcnt == 1) {
                unsigned long long mcur = mhi | (0xFFull << (by * 8));
                for (int e = tid; e < K1; e += NT) {
                    unsigned long long k = s_BK[e];
                    if ((k & mcur) == npref) s_theta = k;   // unique writer
                }
                if (tid == 0) s_done = 1;
            }
            __syncthreads();
        }
        theta = s_theta;    // keys unique (node idx in low bits) => exit guaranteed
    }

    // ---- P8: loss + cross-block finisher (no separate memset kernel) ----
    float acc = 0.0f;
    for (int e = tid; e < K1; e += NT) {
        unsigned rec = s_BAR[e];
        float b = funmap_desc(s_KEY[rec >> 12]);
        float dd = funmap_desc(s_KEY[rec & 0xFFFu]);
        bool mt = (m > 0) && (s_BK[e] <= theta);
        float v1 = (b - 1.0f) * (b - 1.0f) + dd * dd;   // matched vs target (1,0)
        float v0 = 0.5f * (b - dd) * (b - dd);          // unmatched -> diagonal
        acc += mt ? v1 : v0;
    }
    if (tid == 0 && s_K2 > m) acc += 0.5f * (float)(s_K2 - m);  // unmatched (1,0)
    for (int off = 32; off > 0; off >>= 1) acc += __shfl_down(acc, off);
    if (lane == 0) s_f32[wid] = acc;
    __syncthreads();
    if (tid == 0) {
        float ls = 0.0f;
        for (int w = 0; w < 16; ++w) ls += s_f32[w];
        if (smp != 0) {
            // losses >= 0 => sign bit 0 => bits never equal POISON (sign bit 1)
            atomicExch(&wsK[4 + smp], __float_as_uint(ls));
        } else {
            float tot = ls;
            for (int j = 1; j < 4; ++j) {
                unsigned v;
                do { v = atomicAdd(&wsK[4 + j], 0u);
                     __builtin_amdgcn_s_sleep(8);
                } while (v == POISON);
                tot += __uint_as_float(v);
            }
            out[0] = 0.25f * tot;   // unconditional overwrite (out is poisoned)
        }
    }
}

extern "C" void kernel_launch(void* const* d_in, const int* in_sizes, int n_in,
                              void* d_out, int out_size, void* d_ws, size_t ws_size,
                              hipStream_t stream) {
    const float* logits = (const float*)d_in[0];   // (4,2,64,64) f32
    const float* target = (const float*)d_in[1];   // (4,64,64) f32
    unsigned* wsK = (unsigned*)d_ws;               // [0..3] K2 tags, [4..7] loss bits

    hipLaunchKernelGGL(betti_fused_kernel, dim3(8), dim3(NT), 0, stream,
                       logits, target, (float*)d_out, wsK);
}